// Round 13
// baseline (240.963 us; speedup 1.0000x reference)
//
#include <hip/hip_runtime.h>

#define N_NODES 50000
#define N_REL 8
#define N_EDGES 64000
#define D 128
#define TR 16        // dst rows per tile
#define NT 3125      // N_NODES / TR exactly
#define CAP 64       // per-(rel,tile) bucket cap: Poisson(20.5), ~9.6 sigma
#define CROW 16      // per-(rel,row) list cap: Poisson(1.28), P(>=16)~7e-13
#define SLABW 66     // uints per slab row (264 B)

typedef __attribute__((ext_vector_type(8))) short short8;
typedef __attribute__((ext_vector_type(4))) float f32x4;

__device__ __forceinline__ unsigned short f2bf(float x) {
  unsigned int u = __float_as_uint(x);
  u += 0x7FFFu + ((u >> 16) & 1u);
  return (unsigned short)(u >> 16);
}
__device__ __forceinline__ float bflo(unsigned v) { return __uint_as_float(v << 16); }
__device__ __forceinline__ float bfhi(unsigned v) { return __uint_as_float(v & 0xFFFF0000u); }
__device__ __forceinline__ unsigned packbf(float x, float y) {
  return (unsigned)f2bf(x) | ((unsigned)f2bf(y) << 16);
}

// ---- K1: degree counts only ----
__global__ __launch_bounds__(256) void count_kernel(
    const int* __restrict__ src, const int* __restrict__ dst,
    int* __restrict__ outc, int* __restrict__ inc) {
  int i = blockIdx.x * 256 + threadIdx.x;  // < 512000
  int r = i / N_EDGES;
  atomicAdd(&outc[r * N_NODES + src[i]], 1);
  atomicAdd(&inc[r * N_NODES + dst[i]], 1);
}

// ---- K2: bucket place (coeff = osc[s] only) + F->bf16x2 + W->bf16[r][n][k] + bias ----
__global__ __launch_bounds__(256) void place_conv_kernel(
    const int* __restrict__ src, const int* __restrict__ dst,
    const float* __restrict__ F, const float* __restrict__ W,
    const float* __restrict__ b, const int* __restrict__ outc,
    int* __restrict__ bcnt, uint2* __restrict__ buckets,
    uint2* __restrict__ F16, unsigned short* __restrict__ Wt,
    float* __restrict__ bs) {
  int bid = blockIdx.x, t = threadIdx.x;
  if (bid < 2000) {  // N_REL*N_EDGES = 512000
    int i = bid * 256 + t;
    int r = i / N_EDGES;
    int s = src[i], d = dst[i];
    float c = rsqrtf(fmaxf((float)outc[r * N_NODES + s], 1.0f));
    int tile = d >> 4;
    int slot = atomicAdd(&bcnt[r * NT + tile], 1);
    if (slot < CAP)
      buckets[(size_t)(r * NT + tile) * CAP + slot] =
          make_uint2((unsigned)s | ((unsigned)(d & 15) << 17),
                     __float_as_uint(c));
  } else if (bid < 8250) {  // N_NODES*32 = 1.6M float4s
    int i = (bid - 2000) * 256 + t;
    float4 v = ((const float4*)F)[i];
    uint2 o;
    o.x = packbf(v.x, v.y);
    o.y = packbf(v.z, v.w);
    F16[i] = o;
  } else {  // N_REL*D*D = 512*256
    int i = (bid - 8250) * 256 + t;
    int r = i >> 14, rem = i & 16383, n = rem >> 7, k = rem & 127;
    Wt[i] = f2bf(W[(r << 14) + (k << 7) + n]);
    if (bid == 8250 && t < D) {
      float v = 0.f;
#pragma unroll
      for (int rr = 0; rr < N_REL; ++rr) v += b[rr * D + t];
      bs[t] = v;
    }
  }
}

// ---- fused: 1 tile/block, 16 waves; wave w owns dst row w (register gather) ----
// Stage: waves 0-7 scatter rel-w descs into per-(rel,row) LDS lists (LDS
// atomics). Gather: wave w accumulates row w for all 8 rels in 2 f32 regs
// (~1.3 edges/rel; wave-uniform branch, chain-free), applies isc, writes one
// slab word. MFMA: waves 0-7, col-slice w, B streamed from L2-hot Wt.
__global__ __launch_bounds__(1024) void fused_kernel(
    const unsigned int* __restrict__ F16,   // [N][64] packed bf16x2
    const unsigned short* __restrict__ Wt,  // [8][n=128][k=128]
    const int* __restrict__ inc,            // [8][N] in-degree counts
    const int* __restrict__ bcnt,           // [8][NT]
    const uint2* __restrict__ buckets,      // [8][NT][CAP]
    const float* __restrict__ bs,           // [128]
    float* __restrict__ out) {
  __shared__ unsigned slabs[8][TR * SLABW];  // 33792 B
  __shared__ uint2 dl[8][TR][CROW];          // 16384 B
  __shared__ int c2[8][TR];                  // 512 B
  int tid = threadIdx.x;
  int lane = tid & 63;
  int w = tid >> 6;  // 0..15
  int l15 = lane & 15, g = lane >> 4;
  int t = blockIdx.x, t0 = t * TR;

  if (tid < 128) ((int*)c2)[tid] = 0;
  __syncthreads();

  // stage + per-row scatter (waves 0-7, rel = w)
  if (w < 8) {
    int nn = min(bcnt[w * NT + t], CAP);
    if (lane < nn) {
      uint2 e = buckets[(size_t)(w * NT + t) * CAP + lane];
      int row = (e.x >> 17) & 15;
      int slot = atomicAdd(&c2[w][row], 1);
      if (slot < CROW) dl[w][row][slot] = e;
    }
  }
  __syncthreads();

  // register gather: wave w owns row t0+w, all 8 relations
#pragma unroll
  for (int r = 0; r < 8; ++r) {
    int n2 = min(c2[r][w], CROW);  // wave-uniform
    float ax = 0.f, ay = 0.f;
    for (int i = 0; i < n2; ++i) {
      uint2 e = dl[r][w][i];  // LDS broadcast
      int s = e.x & 0x1FFFF;
      float c = __uint_as_float(e.y);
      unsigned fv = F16[(unsigned)s * 64 + lane];
      ax = fmaf(c, bflo(fv), ax);
      ay = fmaf(c, bfhi(fv), ay);
    }
    float ic = rsqrtf(fmaxf((float)inc[r * N_NODES + t0 + w], 1.0f));
    slabs[r][w * SLABW + lane] = packbf(ax * ic, ay * ic);
  }
  __syncthreads();

  // MFMA: waves 0-7, cols [w*16, w*16+16); B streamed (L2-hot, 16KB/block)
  if (w < 8) {
    f32x4 acc = (f32x4){0.f, 0.f, 0.f, 0.f};
    const unsigned short* wb = Wt + (w * 16 + l15) * D + g * 8;
#pragma unroll
    for (int r = 0; r < 8; ++r)
#pragma unroll
      for (int ks = 0; ks < 4; ++ks) {
        short8 B = *(const short8*)&wb[(size_t)r * D * D + ks * 32];
        short8 A = *(const short8*)&slabs[r][l15 * SLABW + ks * 16 + g * 4];
        acc = __builtin_amdgcn_mfma_f32_16x16x32_bf16(A, B, acc, 0, 0, 0);
      }
    // epilogue: C/D col=lane&15, row=4*(lane>>4)+reg
    int col = w * 16 + l15;
    float bias = bs[col];
#pragma unroll
    for (int q = 0; q < 4; ++q)
      out[(size_t)(t0 + g * 4 + q) * D + col] = acc[q] + bias;
  }
}

extern "C" void kernel_launch(void* const* d_in, const int* in_sizes, int n_in,
                              void* d_out, int out_size, void* d_ws, size_t ws_size,
                              hipStream_t stream) {
  const float* F = (const float*)d_in[0];  // [50000,128]
  const float* W = (const float*)d_in[1];  // [8,128,128]
  const float* b = (const float*)d_in[2];  // [8,128]
  const int* src = (const int*)d_in[3];    // [8,64000]
  const int* dst = (const int*)d_in[4];    // [8,64000]
  float* out = (float*)d_out;              // [50000,128]

  char* ws = (char*)d_ws;
  size_t o = 0;
  int* outc = (int*)(ws + o);  o += (size_t)N_REL * N_NODES * 4;  // 1.6 MB
  int* inc = (int*)(ws + o);   o += (size_t)N_REL * N_NODES * 4;  // 1.6 MB
  int* bcnt = (int*)(ws + o);  o += (size_t)N_REL * NT * 4;       // 100 KB
  size_t zero_bytes = o;  // outc, inc, bcnt contiguous
  uint2* buckets = (uint2*)(ws + o);              o += (size_t)N_REL * NT * CAP * 8;  // 12.8 MB
  unsigned int* F16 = (unsigned int*)(ws + o);    o += (size_t)N_NODES * 64 * 4;      // 12.8 MB
  unsigned short* Wt = (unsigned short*)(ws + o); o += (size_t)N_REL * D * D * 2;
  float* bs = (float*)(ws + o);                   o += D * 4;

  hipMemsetAsync(outc, 0, zero_bytes, stream);
  count_kernel<<<2000, 256, 0, stream>>>(src, dst, outc, inc);
  place_conv_kernel<<<8762, 256, 0, stream>>>(src, dst, F, W, b, outc, bcnt,
                                              buckets, (uint2*)F16, Wt, bs);
  fused_kernel<<<NT, 1024, 0, stream>>>(F16, Wt, inc, bcnt, buckets, bs, out);
}

// Round 14
// 183.320 us; speedup vs baseline: 1.3144x; 1.3144x over previous
//
#include <hip/hip_runtime.h>

#define N_NODES 50000
#define N_REL 8
#define N_EDGES 64000
#define D 128
#define TROWS 32
#define NT 1563      // ceil(N_NODES/32)
#define CAP 128      // bucket cap: Poisson mean 41, 13 sigma headroom
#define SLABW 66     // uints per slab row (264 B, 2-way banks = free)
#define GRID 256     // persistent, 1 block/CU (R7-proven)
#define RSTR 80      // F16X row stride in dwords (320 B): 64 data + 8 osc + 8 pad

typedef __attribute__((ext_vector_type(8))) short short8;
typedef __attribute__((ext_vector_type(4))) float f32x4;

__device__ __forceinline__ unsigned short f2bf(float x) {
  unsigned int u = __float_as_uint(x);
  u += 0x7FFFu + ((u >> 16) & 1u);
  return (unsigned short)(u >> 16);
}
__device__ __forceinline__ float bflo(unsigned v) { return __uint_as_float(v << 16); }
__device__ __forceinline__ float bfhi(unsigned v) { return __uint_as_float(v & 0xFFFF0000u); }
__device__ __forceinline__ unsigned packbf(float x, float y) {
  return (unsigned)f2bf(x) | ((unsigned)f2bf(y) << 16);
}

// ---- K1: degree counts ([N][8] layout) + bucket place (4B descs, no coeff)
//          + W->bf16 [r][n][k] + bias sum ----
__global__ __launch_bounds__(256) void k1_kernel(
    const int* __restrict__ src, const int* __restrict__ dst,
    const float* __restrict__ W, const float* __restrict__ b,
    int* __restrict__ outc, int* __restrict__ inc, int* __restrict__ bcnt,
    unsigned* __restrict__ bdesc, unsigned short* __restrict__ Wt,
    float* __restrict__ bs) {
  int bid = blockIdx.x, t = threadIdx.x;
  if (bid < 2000) {  // N_REL*N_EDGES = 512000
    int i = bid * 256 + t;
    int r = i / N_EDGES;
    int s = src[i], d = dst[i];
    atomicAdd(&outc[s * 8 + r], 1);
    atomicAdd(&inc[d * 8 + r], 1);
    int tile = d >> 5;
    int slot = atomicAdd(&bcnt[r * NT + tile], 1);
    if (slot < CAP)
      bdesc[(size_t)(r * NT + tile) * CAP + slot] =
          (unsigned)s | ((unsigned)(d & 31) << 17);
  } else {  // N_REL*D*D = 512*256 W elements
    int i = (bid - 2000) * 256 + t;
    int r = i >> 14, rem = i & 16383, n = rem >> 7, k = rem & 127;
    Wt[i] = f2bf(W[(r << 14) + (k << 7) + n]);
    if (bid == 2000 && t < D) {
      float v = 0.f;
#pragma unroll
      for (int rr = 0; rr < N_REL; ++rr) v += b[rr * D + t];
      bs[t] = v;
    }
  }
}

// ---- K2: build F16X rows: [N][80] dwords = 64 packed-bf16 + 8 osc + pad ----
__global__ __launch_bounds__(256) void k2_kernel(
    const float* __restrict__ F, const int* __restrict__ outc,
    unsigned* __restrict__ F16X) {
  int i = blockIdx.x * 256 + threadIdx.x;  // 800000 = 3125*256: node n, chunk c
  int n = i >> 4, c = i & 15;
  const float4* F4 = (const float4*)F;
  float4 a = F4[n * 32 + c * 2];
  float4 q = F4[n * 32 + c * 2 + 1];
  uint4 o;
  o.x = packbf(a.x, a.y);
  o.y = packbf(a.z, a.w);
  o.z = packbf(q.x, q.y);
  o.w = packbf(q.z, q.w);
  *(uint4*)(F16X + (size_t)n * RSTR + c * 4) = o;
  if (c < 8)
    F16X[(size_t)n * RSTR + 64 + c] =
        __float_as_uint(rsqrtf(fmaxf((float)outc[n * 8 + c], 1.0f)));
}

// ---- fused: R7 structure; persistent; wave w = relation w (gather) +
//      col-slice w (GEMM). Coeff osc_r[s] read from the SAME F16X row block
//      (one random stream); isc per-row from inc[N][8], staged to LDS. ----
__global__ __launch_bounds__(512, 2) void fused_kernel(
    const unsigned int* __restrict__ F16X,  // [N][80]
    const unsigned short* __restrict__ Wt,  // [8][n=128][k=128]
    const int* __restrict__ inc,            // [N][8]
    const int* __restrict__ bcnt,           // [8][NT]
    const unsigned* __restrict__ bdesc,     // [8][NT][CAP]
    const float* __restrict__ bs,           // [128]
    float* __restrict__ out) {
  __shared__ unsigned slabs[8][TROWS * SLABW];  // 67584 B
  __shared__ unsigned dlds[8][CAP];             // 4096 B
  __shared__ float iscl[8][TROWS];              // 1024 B
  int tid = threadIdx.x;
  int lane = tid & 63;
  int w = __builtin_amdgcn_readfirstlane(tid >> 6);
  int l15 = lane & 15, g = lane >> 4;

  // B-frags (compiler remats from L2 as needed — R7-proven)
  short8 bfr[8][4];
#pragma unroll
  for (int r = 0; r < 8; ++r)
#pragma unroll
    for (int ks = 0; ks < 4; ++ks)
      bfr[r][ks] = *(const short8*)&Wt[(size_t)r * D * D +
                                       (w * 16 + l15) * D + ks * 32 + g * 8];
  float bias = bs[w * 16 + l15];

#define RMW(dd, cc, fv)                                       \
  {                                                           \
    int row_ = ((dd) >> 17) & 31;                             \
    unsigned* p_ = &slabs[w][row_ * SLABW + lane];            \
    unsigned old_ = *p_;                                      \
    *p_ = packbf(fmaf(cc, bflo(fv), bflo(old_)),              \
                 fmaf(cc, bfhi(fv), bfhi(old_)));             \
  }

  for (int t = blockIdx.x; t < NT; t += GRID) {
    __syncthreads();  // prior tile's MFMA reads of slabs complete

    // zero own slab
    for (int i = lane; i < TROWS * SLABW; i += 64) slabs[w][i] = 0u;

    // stage descriptors + per-row isc
    int t0 = t * TROWS;
    int n = min(bcnt[w * NT + t], CAP);
    const unsigned* bk = &bdesc[(size_t)(w * NT + t) * CAP];
    if (lane < n) dlds[w][lane] = bk[lane];
    if (lane + 64 < n) dlds[w][lane + 64] = bk[lane + 64];
    if (lane < TROWS) {
      int row = t0 + lane;
      iscl[w][lane] =
          (row < N_NODES) ? rsqrtf(fmaxf((float)inc[row * 8 + w], 1.0f)) : 0.f;
    }

    // gather own relation (coeff from row block word 64+w)
    int i = 0;
    for (; i + 4 <= n; i += 4) {
      unsigned d0 = dlds[w][i], d1 = dlds[w][i + 1], d2 = dlds[w][i + 2],
               d3 = dlds[w][i + 3];
      unsigned s0 = d0 & 0x1FFFF, s1 = d1 & 0x1FFFF, s2 = d2 & 0x1FFFF,
               s3 = d3 & 0x1FFFF;
      unsigned f0 = F16X[(size_t)s0 * RSTR + lane];
      unsigned f1 = F16X[(size_t)s1 * RSTR + lane];
      unsigned f2 = F16X[(size_t)s2 * RSTR + lane];
      unsigned f3 = F16X[(size_t)s3 * RSTR + lane];
      float c0 = __uint_as_float(F16X[(size_t)s0 * RSTR + 64 + w]);
      float c1 = __uint_as_float(F16X[(size_t)s1 * RSTR + 64 + w]);
      float c2 = __uint_as_float(F16X[(size_t)s2 * RSTR + 64 + w]);
      float c3 = __uint_as_float(F16X[(size_t)s3 * RSTR + 64 + w]);
      RMW(d0, c0, f0) RMW(d1, c1, f1) RMW(d2, c2, f2) RMW(d3, c3, f3)
    }
    for (; i < n; ++i) {
      unsigned dd = dlds[w][i];
      unsigned s0 = dd & 0x1FFFF;
      unsigned fv = F16X[(size_t)s0 * RSTR + lane];
      float c0 = __uint_as_float(F16X[(size_t)s0 * RSTR + 64 + w]);
      RMW(dd, c0, fv)
    }

    // isc row-scale pass (uniform LDS-staged scale)
#pragma unroll
    for (int ii = 0; ii < TROWS; ++ii) {
      float c = iscl[w][ii];
      unsigned v = slabs[w][ii * SLABW + lane];
      slabs[w][ii * SLABW + lane] = packbf(bflo(v) * c, bfhi(v) * c);
    }

    __syncthreads();  // all 8 slabs ready

    // GEMM: acc += sum_r A_r(32x128) x B_r[:, w*16..+16)
    f32x4 a0 = (f32x4){0.f, 0.f, 0.f, 0.f};
    f32x4 a1 = (f32x4){0.f, 0.f, 0.f, 0.f};
#pragma unroll
    for (int r = 0; r < 8; ++r) {
#pragma unroll
      for (int ks = 0; ks < 4; ++ks) {
        short8 A0 = *(const short8*)&slabs[r][l15 * SLABW + ks * 16 + g * 4];
        short8 A1 =
            *(const short8*)&slabs[r][(16 + l15) * SLABW + ks * 16 + g * 4];
        a0 = __builtin_amdgcn_mfma_f32_16x16x32_bf16(A0, bfr[r][ks], a0, 0, 0, 0);
        a1 = __builtin_amdgcn_mfma_f32_16x16x32_bf16(A1, bfr[r][ks], a1, 0, 0, 0);
      }
    }

    // epilogue: C/D col=lane&15, row=4*(lane>>4)+reg
    int col = w * 16 + l15;
#pragma unroll
    for (int q = 0; q < 4; ++q) {
      int row0 = t0 + g * 4 + q;
      if (row0 < N_NODES) out[(size_t)row0 * D + col] = a0[q] + bias;
      int row1 = t0 + 16 + g * 4 + q;
      if (row1 < N_NODES) out[(size_t)row1 * D + col] = a1[q] + bias;
    }
  }
#undef RMW
}

extern "C" void kernel_launch(void* const* d_in, const int* in_sizes, int n_in,
                              void* d_out, int out_size, void* d_ws, size_t ws_size,
                              hipStream_t stream) {
  const float* F = (const float*)d_in[0];  // [50000,128]
  const float* W = (const float*)d_in[1];  // [8,128,128]
  const float* b = (const float*)d_in[2];  // [8,128]
  const int* src = (const int*)d_in[3];    // [8,64000]
  const int* dst = (const int*)d_in[4];    // [8,64000]
  float* out = (float*)d_out;              // [50000,128]

  char* ws = (char*)d_ws;
  size_t o = 0;
  int* outc = (int*)(ws + o);  o += (size_t)N_NODES * 8 * 4;  // 1.6 MB [N][8]
  int* inc = (int*)(ws + o);   o += (size_t)N_NODES * 8 * 4;  // 1.6 MB [N][8]
  int* bcnt = (int*)(ws + o);  o += (size_t)N_REL * NT * 4;   // 50 KB
  size_t zero_bytes = o;  // outc, inc, bcnt contiguous
  unsigned* bdesc = (unsigned*)(ws + o);          o += (size_t)N_REL * NT * CAP * 4;  // 6.4 MB
  unsigned int* F16X = (unsigned int*)(ws + o);   o += (size_t)N_NODES * RSTR * 4;    // 16 MB
  unsigned short* Wt = (unsigned short*)(ws + o); o += (size_t)N_REL * D * D * 2;
  float* bs = (float*)(ws + o);                   o += D * 4;

  hipMemsetAsync(outc, 0, zero_bytes, stream);
  k1_kernel<<<2512, 256, 0, stream>>>(src, dst, W, b, outc, inc, bcnt, bdesc,
                                      Wt, bs);
  k2_kernel<<<3125, 256, 0, stream>>>(F, outc, F16X);
  fused_kernel<<<GRID, 512, 0, stream>>>(F16X, Wt, inc, bcnt, bdesc, bs, out);
}